// Round 1
// baseline (116.478 us; speedup 1.0000x reference)
//
#include <hip/hip_runtime.h>
#include <stdint.h>
#include <math.h>

#define NROWS 8192
#define DDIM  256
#define BM    128
#define BN    128
#define GJ    8                         // column groups (grid.y)
#define COLS_PER_GROUP (NROWS / GJ)     // 1024

constexpr float INV_T  = 1.0f / 0.07f;  // fixed LSE max M0 = 1/T (|logit| <= 1/T)
constexpr float LOG2E  = 1.44269504f;
constexpr float K1     = INV_T * LOG2E; // exp2 arg: fma(acc, K1, -K1)

typedef __bf16 bf16x8 __attribute__((ext_vector_type(8)));
typedef float  f32x4  __attribute__((ext_vector_type(4)));

__device__ __forceinline__ void async_copy16(const uint16_t* g, uint16_t* l) {
    __builtin_amdgcn_global_load_lds(
        (const __attribute__((address_space(1))) uint32_t*)g,
        (__attribute__((address_space(3))) uint32_t*)l, 16, 0, 0);
}

__device__ inline uint16_t f2bf(float f) {
    uint32_t u = __float_as_uint(f);
    u += 0x7fffu + ((u >> 16) & 1u);    // RNE
    return (uint16_t)(u >> 16);
}

// Kernel 1: normalize each row to unit length, emit bf16. One wave per row.
__global__ __launch_bounds__(256) void norm_convert_kernel(
    const float* __restrict__ fq, const float* __restrict__ fk,
    uint16_t* __restrict__ qb, uint16_t* __restrict__ kb)
{
    const int wave = threadIdx.x >> 6;
    const int lane = threadIdx.x & 63;
    const int row  = blockIdx.x * 4 + wave;

    const float* src; uint16_t* dstb;
    if (row < NROWS) {
        src = fq + (size_t)row * DDIM; dstb = qb + (size_t)row * DDIM;
    } else {
        int r = row - NROWS;
        src = fk + (size_t)r * DDIM; dstb = kb + (size_t)r * DDIM;
    }

    float4 v = ((const float4*)src)[lane];
    float ss = v.x*v.x + v.y*v.y + v.z*v.z + v.w*v.w;
    #pragma unroll
    for (int m = 1; m < 64; m <<= 1) ss += __shfl_xor(ss, m, 64);
    float r = rsqrtf(ss);

    ushort4 o;
    o.x = f2bf(v.x * r); o.y = f2bf(v.y * r); o.z = f2bf(v.z * r); o.w = f2bf(v.w * r);
    ((ushort4*)dstb)[lane] = o;
}

// Kernel 2: fused GEMM + fixed-max sum-of-exp over this block's 1024-col group.
// Q fragments live entirely in registers (loaded once from global, reused by all
// 8 column tiles). K streams through a 4-deep ring of BK=32 LDS buffers with
// counted-vmcnt barriers (prefetch distance 3, never drained in the main loop).
// Block: 4 waves in 2x2, each 64x64 via 16x16x32 bf16 MFMA.
__global__ __launch_bounds__(256, 2) void nce_main_kernel(
    const uint16_t* __restrict__ qb, const uint16_t* __restrict__ kb,
    float* __restrict__ lpT, float* __restrict__ gpl)
{
    __shared__ __align__(16) uint16_t lds_k[4 * BN * 32];   // 4 ring bufs x 8 KiB = 32 KiB

    const int tid    = threadIdx.x;
    const int wave   = tid >> 6;
    const int lane   = tid & 63;
    const int quad   = lane >> 4;
    const int lanelo = lane & 15;
    const int wr     = wave >> 1;
    const int wc     = wave & 1;
    const int rowBase      = blockIdx.x * BM;
    const int colGroupBase = blockIdx.y * COLS_PER_GROUP;

    // ---- Q fragments straight into registers (128 VGPR), loaded exactly once.
    // Lane reads 16B at row (wr*64+mt*16+lanelo), byte offset kk*64 + quad*16:
    // per 16-lane row-group the 4 quads cover a contiguous 64B segment.
    bf16x8 aq[4][8];
    #pragma unroll
    for (int mt = 0; mt < 4; ++mt) {
        const uint16_t* qrow =
            qb + (size_t)(rowBase + wr * 64 + mt * 16 + lanelo) * DDIM + quad * 8;
        #pragma unroll
        for (int kk = 0; kk < 8; ++kk)
            aq[mt][kk] = *(const bf16x8*)(qrow + kk * 32);
    }

    // ---- K staging lane constants (chunk = 16B; 4 chunks per 32-col row).
    // Source pre-swizzle matches the XOR on the read side (kills row-stride
    // bank conflicts; global_load_lds dest must stay linear).
    int kS0   = wave * 128 + lane;                      // i=0 chunk id in 512-chunk buffer
    int krow0 = kS0 >> 2;
    int kch0  = (lane & 3) ^ (krow0 & 3);
    int krow1 = (kS0 + 64) >> 2;
    int kch1  = (lane & 3) ^ (krow1 & 3);
    const uint16_t* kbase0 = kb + (size_t)(colGroupBase + krow0) * DDIM + kch0 * 8;
    const uint16_t* kbase1 = kb + (size_t)(colGroupBase + krow1) * DDIM + kch1 * 8;

    // ---- Prologue: chunks 0..2 into ring bufs 0..2 (6 loads in flight/wave).
    #pragma unroll
    for (int p = 0; p < 3; ++p) {
        uint16_t* ld = lds_k + (p << 12) + (wave << 10);
        async_copy16(kbase0 + (p << 5), ld);
        async_copy16(kbase1 + (p << 5), ld + 512);
    }

    int bvoff[4];
    #pragma unroll
    for (int nt = 0; nt < 4; ++nt) {
        int rk = wc * 64 + nt * 16 + lanelo;
        bvoff[nt] = rk * 32 + (quad ^ (rk & 3)) * 8;
    }

    float l_run[16];
    #pragma unroll
    for (int i = 0; i < 16; ++i) l_run[i] = 0.f;

    for (int jt = 0; jt < 8; ++jt) {
        const int colT = colGroupBase + jt * BN;

        f32x4 acc[4][4];
        #pragma unroll
        for (int mt = 0; mt < 4; ++mt)
            #pragma unroll
            for (int nt = 0; nt < 4; ++nt)
                acc[mt][nt] = (f32x4){0.f, 0.f, 0.f, 0.f};

        #pragma unroll
        for (int kk = 0; kk < 8; ++kk) {
            const int p = (jt << 3) + kk;

            // Counted wait: outstanding = chunks p,p+1,p+2 (6 loads); leaving 4
            // in flight guarantees chunk p's two loads have landed in LDS.
            // The "memory" clobber also fences last iteration's ds_reads above
            // the barrier (WAR safety for the ring reuse).
            asm volatile("s_waitcnt vmcnt(4)" ::: "memory");
            __builtin_amdgcn_s_barrier();

            // Issue chunk p+3 AFTER the barrier (overwrites buf (p-1)&3, whose
            // readers all passed the barrier). Tail issues wrap the source
            // index: content never read, drained by the final __syncthreads.
            {
                const int np  = p + 3;
                const int npm = np & 63;
                const int off = ((npm >> 3) << 15) + ((npm & 7) << 5);
                uint16_t* ld = lds_k + ((np & 3) << 12) + (wave << 10);
                async_copy16(kbase0 + off, ld);
                async_copy16(kbase1 + off, ld + 512);
            }

            // Compute chunk p from ring buf p&3: 4 ds_read_b128 + 16 MFMA.
            bf16x8 bv[4];
            const int bufo = (p & 3) << 12;
            #pragma unroll
            for (int nt = 0; nt < 4; ++nt)
                bv[nt] = *(const bf16x8*)&lds_k[bufo + bvoff[nt]];

            __builtin_amdgcn_s_setprio(1);
            #pragma unroll
            for (int mt = 0; mt < 4; ++mt)
                #pragma unroll
                for (int nt = 0; nt < 4; ++nt)
                    acc[mt][nt] = __builtin_amdgcn_mfma_f32_16x16x32_bf16(
                        aq[mt][kk], bv[nt], acc[mt][nt], 0, 0, 0);
            __builtin_amdgcn_s_setprio(0);
        }

        // Epilogue: fixed-max exp accumulate (registers only).
        int gcol[4];
        #pragma unroll
        for (int nt = 0; nt < 4; ++nt) gcol[nt] = colT + wc * 64 + nt * 16 + lanelo;
        #pragma unroll
        for (int mt = 0; mt < 4; ++mt) {
            #pragma unroll
            for (int rg = 0; rg < 4; ++rg) {
                int grow = rowBase + wr * 64 + mt * 16 + quad * 4 + rg;
                float s = 0.f;
                #pragma unroll
                for (int nt = 0; nt < 4; ++nt) {
                    float a = acc[mt][nt][rg];
                    float e = exp2f(fmaf(a, K1, -K1));
                    if (grow == gcol[nt]) { lpT[grow] = a * INV_T; e = 0.f; }  // diag term ~e^-157
                    s += e;
                }
                l_run[mt * 4 + rg] += s;
            }
        }
    }

    // Cross-lane reduce over the 16 lanelo lanes (same row, different cols).
    #pragma unroll
    for (int i = 0; i < 16; ++i) {
        float v = l_run[i];
        v += __shfl_xor(v, 1, 64);
        v += __shfl_xor(v, 2, 64);
        v += __shfl_xor(v, 4, 64);
        v += __shfl_xor(v, 8, 64);
        l_run[i] = v;
    }

    // Drain wrap prefetch DMAs (they target bufs 0..2 = our scratch region)
    // and resync all waves before reusing lds_k.
    __syncthreads();

    float* pl = (float*)lds_k;      // 256 floats scratch
    if (lanelo == 0) {
        #pragma unroll
        for (int mt = 0; mt < 4; ++mt)
            #pragma unroll
            for (int rg = 0; rg < 4; ++rg) {
                int lr = wr * 64 + mt * 16 + quad * 4 + rg;
                pl[wc * 128 + lr] = l_run[mt * 4 + rg];
            }
    }
    __syncthreads();
    if (tid < 128) {
        float L = pl[tid] + pl[128 + tid];
        gpl[(size_t)blockIdx.y * NROWS + rowBase + tid] = L;
    }
}

// Kernel 3: merge GJ partial sums + l_pos; loss = M0 + log(L) - l_pos/T.
__global__ __launch_bounds__(256) void finalize_kernel(
    const float* __restrict__ gpl, const float* __restrict__ lpT,
    float* __restrict__ out)
{
    int t = blockIdx.x * 256 + threadIdx.x;
    if (t >= NROWS) return;
    float L = 0.f;
    #pragma unroll
    for (int g = 0; g < GJ; ++g) L += gpl[g * NROWS + t];
    float lp = lpT[t];
    L += __expf(lp - INV_T);
    out[t] = INV_T + __logf(L) - lp;
}

extern "C" void kernel_launch(void* const* d_in, const int* in_sizes, int n_in,
                              void* d_out, int out_size, void* d_ws, size_t ws_size,
                              hipStream_t stream) {
    const float* fq = (const float*)d_in[0];
    const float* fk = (const float*)d_in[1];
    char* ws = (char*)d_ws;
    // layout: qb 4MB | kb 4MB | lpT 32KB | gpl 256KB
    uint16_t* qb  = (uint16_t*)(ws);
    uint16_t* kb  = (uint16_t*)(ws + 4194304);
    float*    lpT = (float*)(ws + 8388608);
    float*    gpl = (float*)(ws + 8421376);

    norm_convert_kernel<<<(2 * NROWS) / 4, 256, 0, stream>>>(fq, fk, qb, kb);
    dim3 grid(NROWS / BM, GJ);
    nce_main_kernel<<<grid, 256, 0, stream>>>(qb, kb, lpT, gpl);
    finalize_kernel<<<NROWS / 256, 256, 0, stream>>>(gpl, lpT, (float*)d_out);
}